// Round 1
// baseline (96.996 us; speedup 1.0000x reference)
//
#include <hip/hip_runtime.h>

#define FWHT_D 4096

// Involutive LDS swizzle: XOR float-index bits 2..4 with bits 6..8.
// Keeps 16B alignment (bits 0..1 untouched); makes all four access
// patterns below conflict-free (hand-verified bank math).
static __device__ __forceinline__ int swz(int i) {
    return i ^ (((i >> 6) & 7) << 2);
}

static __device__ __forceinline__ void bfly(float& a, float& b) {
    float s = a + b;
    float d = a - b;
    a = s; b = d;
}

__global__ __launch_bounds__(256, 2) void fwht_kernel(const float* __restrict__ x,
                                                      const float* __restrict__ signs,
                                                      float* __restrict__ out) {
    __shared__ float lds[FWHT_D];

    const int row = blockIdx.x;
    const int t   = threadIdx.x;          // 0..255
    const float* xr  = x   + (size_t)row * FWHT_D;
    float*       orw = out + (size_t)row * FWHT_D;

    // ---------------- Phase 1: elements i = 1024k + 4t + e ----------------
    // Coalesced float4 loads; stages h = 1, 2 (within float4), 1024, 2048 (across k).
    float4 r[4];
#pragma unroll
    for (int k = 0; k < 4; ++k) {
        const int i = 1024 * k + 4 * t;
        float4 xv = *(const float4*)(xr + i);
        float4 sv = *(const float4*)(signs + i);
        r[k].x = xv.x * sv.x;
        r[k].y = xv.y * sv.y;
        r[k].z = xv.z * sv.z;
        r[k].w = xv.w * sv.w;
    }
#pragma unroll
    for (int k = 0; k < 4; ++k) {
        bfly(r[k].x, r[k].y);   // h = 1
        bfly(r[k].z, r[k].w);
        bfly(r[k].x, r[k].z);   // h = 2
        bfly(r[k].y, r[k].w);
    }
    // h = 1024 : k pairs (0,1),(2,3); h = 2048 : (0,2),(1,3)
#pragma unroll
    for (int pass = 0; pass < 2; ++pass) {
        const int b = 1 << pass;
#pragma unroll
        for (int k = 0; k < 4; ++k) {
            if (!(k & b)) {
                bfly(r[k].x, r[k | b].x);
                bfly(r[k].y, r[k | b].y);
                bfly(r[k].z, r[k | b].z);
                bfly(r[k].w, r[k | b].w);
            }
        }
    }
    // Write to LDS (swizzled, 16B-aligned b128 stores).
#pragma unroll
    for (int k = 0; k < 4; ++k) {
        const int i = 1024 * k + 4 * t;
        *(float4*)&lds[swz(i)] = r[k];
    }
    __syncthreads();

    // ---------------- Phase 2: elements i = B*64 + 4j + c ----------------
    // B = t>>2 (0..63), c = t&3, j = 0..15 -> stages h = 4, 8, 16, 32.
    {
        const int B = t >> 2;
        const int c = t & 3;
        const int s = B & 7;            // == (i>>6)&7 for all j
        float v[16];
#pragma unroll
        for (int j = 0; j < 16; ++j)
            v[j] = lds[(B * 64 + 4 * j + c) ^ (s << 2)];

#pragma unroll
        for (int pass = 0; pass < 4; ++pass) {
            const int b = 1 << pass;    // j-bit -> h = 4<<pass
#pragma unroll
            for (int j = 0; j < 16; ++j)
                if (!(j & b)) bfly(v[j], v[j | b]);
        }

#pragma unroll
        for (int j = 0; j < 16; ++j)
            lds[(B * 64 + 4 * j + c) ^ (s << 2)] = v[j];
    }
    __syncthreads();

    // ---------------- Phase 3: elements i = w*1024 + 64j + l ----------------
    // w = t>>6, l = t&63, j = 0..15 -> stages h = 64, 128, 256, 512.
    {
        const int w = t >> 6;
        const int l = t & 63;
        float v[16];
#pragma unroll
        for (int j = 0; j < 16; ++j)
            v[j] = lds[(1024 * w + 64 * j + l) ^ ((j & 7) << 2)];

#pragma unroll
        for (int pass = 0; pass < 4; ++pass) {
            const int b = 1 << pass;    // j-bit -> h = 64<<pass
#pragma unroll
            for (int j = 0; j < 16; ++j)
                if (!(j & b)) bfly(v[j], v[j | b]);
        }

        // Coalesced scalar stores (lane-consecutive for each j).
#pragma unroll
        for (int j = 0; j < 16; ++j)
            orw[1024 * w + 64 * j + l] = v[j];
    }
}

extern "C" void kernel_launch(void* const* d_in, const int* in_sizes, int n_in,
                              void* d_out, int out_size, void* d_ws, size_t ws_size,
                              hipStream_t stream) {
    const float* x     = (const float*)d_in[0];
    const float* signs = (const float*)d_in[1];
    float* out = (float*)d_out;

    const int rows = in_sizes[0] / FWHT_D;   // 16384 for the given shapes
    dim3 grid(rows), block(256);
    fwht_kernel<<<grid, block, 0, stream>>>(x, signs, out);
}

// Round 3
// 91.450 us; speedup vs baseline: 1.0606x; 1.0606x over previous
//
#include <hip/hip_runtime.h>

#define FWHT_D 4096

typedef float v4f __attribute__((ext_vector_type(4)));

// Involutive LDS swizzle: XOR float-index bits 2..4 with bits 6..8.
// Keeps 16B alignment (bits 0..1 untouched); conflict-free for all four
// access patterns below (0 LDS bank conflicts measured in R1).
static __device__ __forceinline__ int swz(int i) {
    return i ^ (((i >> 6) & 7) << 2);
}

static __device__ __forceinline__ void bfly(float& a, float& b) {
    float s = a + b;
    float d = a - b;
    a = s; b = d;
}

__global__ __launch_bounds__(256, 2) void fwht_kernel(const float* __restrict__ x,
                                                      const float* __restrict__ signs,
                                                      float* __restrict__ out) {
    __shared__ float lds[FWHT_D];

    const int row = blockIdx.x;
    const int t   = threadIdx.x;          // 0..255
    const float* xr  = x   + (size_t)row * FWHT_D;
    float*       orw = out + (size_t)row * FWHT_D;

    // ---------------- Phase 1: elements i = 1024k + 4t + e ----------------
    // Nontemporal float4 loads of x (read-once stream); signs stays cached.
    float r[4][4];
#pragma unroll
    for (int k = 0; k < 4; ++k) {
        const int i = 1024 * k + 4 * t;
        v4f xv = __builtin_nontemporal_load((const v4f*)(xr + i));
        v4f sv = *(const v4f*)(signs + i);
        v4f p  = xv * sv;
        r[k][0] = p.x; r[k][1] = p.y; r[k][2] = p.z; r[k][3] = p.w;
    }
#pragma unroll
    for (int k = 0; k < 4; ++k) {
        bfly(r[k][0], r[k][1]);   // h = 1
        bfly(r[k][2], r[k][3]);
        bfly(r[k][0], r[k][2]);   // h = 2
        bfly(r[k][1], r[k][3]);
    }
    // h = 1024 : k pairs (0,1),(2,3); h = 2048 : (0,2),(1,3)
#pragma unroll
    for (int pass = 0; pass < 2; ++pass) {
        const int b = 1 << pass;
#pragma unroll
        for (int k = 0; k < 4; ++k) {
            if (!(k & b)) {
#pragma unroll
                for (int e = 0; e < 4; ++e)
                    bfly(r[k][e], r[k | b][e]);
            }
        }
    }
    // Write to LDS (swizzled, 16B-aligned b128 stores).
#pragma unroll
    for (int k = 0; k < 4; ++k) {
        const int i = 1024 * k + 4 * t;
        v4f p = { r[k][0], r[k][1], r[k][2], r[k][3] };
        *(v4f*)&lds[swz(i)] = p;
    }
    __syncthreads();

    // ---------------- Phase 2: elements i = B*64 + 4j + c ----------------
    // B = t>>2 (0..63), c = t&3, j = 0..15 -> stages h = 4, 8, 16, 32.
    {
        const int B = t >> 2;
        const int c = t & 3;
        const int s = B & 7;            // == (i>>6)&7 for all j
        float v[16];
#pragma unroll
        for (int j = 0; j < 16; ++j)
            v[j] = lds[(B * 64 + 4 * j + c) ^ (s << 2)];

#pragma unroll
        for (int pass = 0; pass < 4; ++pass) {
            const int b = 1 << pass;    // j-bit -> h = 4<<pass
#pragma unroll
            for (int j = 0; j < 16; ++j)
                if (!(j & b)) bfly(v[j], v[j | b]);
        }

#pragma unroll
        for (int j = 0; j < 16; ++j)
            lds[(B * 64 + 4 * j + c) ^ (s << 2)] = v[j];
    }
    __syncthreads();

    // ---------------- Phase 3: elements i = w*1024 + 64j + l ----------------
    // w = t>>6, l = t&63, j = 0..15 -> stages h = 64, 128, 256, 512.
    {
        const int w = t >> 6;
        const int l = t & 63;
        float v[16];
#pragma unroll
        for (int j = 0; j < 16; ++j)
            v[j] = lds[(1024 * w + 64 * j + l) ^ ((j & 7) << 2)];

#pragma unroll
        for (int pass = 0; pass < 4; ++pass) {
            const int b = 1 << pass;    // j-bit -> h = 64<<pass
#pragma unroll
            for (int j = 0; j < 16; ++j)
                if (!(j & b)) bfly(v[j], v[j | b]);
        }

        // Coalesced nontemporal scalar stores (lane-consecutive per j).
#pragma unroll
        for (int j = 0; j < 16; ++j)
            __builtin_nontemporal_store(v[j], orw + 1024 * w + 64 * j + l);
    }
}

extern "C" void kernel_launch(void* const* d_in, const int* in_sizes, int n_in,
                              void* d_out, int out_size, void* d_ws, size_t ws_size,
                              hipStream_t stream) {
    const float* x     = (const float*)d_in[0];
    const float* signs = (const float*)d_in[1];
    float* out = (float*)d_out;

    const int rows = in_sizes[0] / FWHT_D;   // 16384 for the given shapes
    dim3 grid(rows), block(256);
    fwht_kernel<<<grid, block, 0, stream>>>(x, signs, out);
}